// Round 12
// baseline (321.213 us; speedup 1.0000x reference)
//
#include <hip/hip_runtime.h>

typedef _Float16 v8h __attribute__((ext_vector_type(8)));
typedef _Float16 v2h __attribute__((ext_vector_type(2)));
typedef float    v4f __attribute__((ext_vector_type(4)));
typedef unsigned int u32;

// ---------------- Kernel 1: style modulation s[b][c] = style[b]·mod_weight[c] + bias[c]
__global__ void style_kernel(const float* __restrict__ style,
                             const float* __restrict__ mw,
                             const float* __restrict__ mb,
                             float* __restrict__ s_out) {
    const int b = blockIdx.x;          // 16 blocks
    const int t = threadIdx.x;         // 256 threads
    const int c = t >> 2, q = t & 3;   // 4 threads per channel, 128 elems each
    const float* st = style + b * 512 + q * 128;
    const float* w  = mw + c * 512 + q * 128;
    float acc = 0.f;
    #pragma unroll 8
    for (int i = 0; i < 128; ++i) acc += st[i] * w[i];
    acc += __shfl_xor(acc, 1);
    acc += __shfl_xor(acc, 2);
    if (q == 0) s_out[b * 64 + c] = acc + mb[c];
}

// ---------------- Kernel 2: modulate + demodulate + repack weights into A-fragment layout
// wA layout: [b][tap][ks*4+ot][lane][j] (f16): lane l holds o = ot*16 + (l&15),
// k(channel) = ks*32 + (l>>4)*8 + j  -> mfma_f32_16x16x32 A-operand layout.
__global__ void wprep_kernel(const float* __restrict__ weight,
                             const float* __restrict__ s,
                             _Float16* __restrict__ wA) {
    const int blk = blockIdx.x;            // 1024 = B*O
    const int b = blk >> 6, o = blk & 63;
    const int lane = threadIdx.x;          // 64
    const float* wo = weight + o * 576;    // weight[0][o][c][kh][kw]
    const float* sb = s + b * 64;
    float vals[9];
    float sum = 0.f;
    #pragma unroll
    for (int k = 0; k < 9; ++k) {
        int e = lane + k * 64;             // 0..575
        int c = e / 9;
        float v = wo[e] * sb[c];
        vals[k] = v;
        sum += v * v;
    }
    #pragma unroll
    for (int off = 32; off; off >>= 1) sum += __shfl_xor(sum, off);
    const float demod = 1.f / sqrtf(sum + 1e-8f);
    #pragma unroll
    for (int k = 0; k < 9; ++k) {
        int e = lane + k * 64;
        int c = e / 9, tap = e - c * 9;
        int ks = c >> 5, lg = (c >> 3) & 3, j = c & 7;
        int dst = (((b * 9 + tap) * 8 + ks * 4 + (o >> 4)) * 64 + lg * 16 + (o & 15)) * 8 + j;
        wA[dst] = (_Float16)(vals[k] * demod);
    }
}

// ---------------- Kernel 3: FUSED conv, 16x16 tile, 3 blocks/CU.
// Per halo row r: stream raw f32 [c][24w] into 2-slot LDS ring via pure
// global_load_lds (dest linear 16*i; no register consumer -> no per-load stall),
// counted per-wave vmcnt + barrier, then LDS->LDS transpose (f32->f16, pack 8
// channels/granule, XOR-swizzled pixel-major lt = layout of the proven compute),
// lgkmcnt+barrier, issue row r+2. Compute phase identical to round-2 (verified).
__global__ __launch_bounds__(256, 3)
void conv_fused(const float* __restrict__ x,
                const _Float16* __restrict__ wA,
                float* __restrict__ out) {
    __shared__ float raw[2 * 1536];                   // 12288 B: [slot][c*24+col]
    __shared__ __align__(16) _Float16 lt[324 * 64];   // 41472 B

    const int tid = threadIdx.x;
    // flatten grid (16,16,16)=4096; 512 consecutive tiles per XCD
    const int fid = blockIdx.x + (blockIdx.y << 4) + (blockIdx.z << 8);
    const int vid = ((fid & 7) << 9) + (fid >> 3);
    const int tx = vid & 15, ty = (vid >> 4) & 15, b = vid >> 8;
    const int h0 = ty << 4, w0 = tx << 4;

    const int lane = tid & 63, wv = tid >> 6;
    const float* xb = x + ((size_t)b << 22);

    // staging slot assignment: i1 = tid (all), i2 = 256+tid (tid<128)
    // slot i -> c = i/6, quad q = i%6, src w = w0-4+4q (clamped); dest = 16*i
    const int i1 = tid;
    const int c1 = i1 / 6, q1 = i1 - c1 * 6;
    const int wq1 = min(max(w0 - 4 + (q1 << 2), 0), 252);
    const int i2 = 256 + tid;
    const int c2 = i2 / 6, q2 = i2 - c2 * 6;
    const int wq2 = min(max(w0 - 4 + (q2 << 2), 0), 252);
    const bool has2 = tid < 128;

    auto issue = [&](int r) {
        const int rc = min(max(h0 - 1 + r, 0), 255);
        float* slot = raw + ((r & 1) ? 1536 : 0);
        const float* s1 = xb + ((size_t)c1 << 16) + (rc << 8) + wq1;
        __builtin_amdgcn_global_load_lds(
            (const __attribute__((address_space(1))) void*)s1,
            (__attribute__((address_space(3))) void*)(slot + i1 * 4), 16, 0, 0);
        if (has2) {
            const float* s2 = xb + ((size_t)c2 << 16) + (rc << 8) + wq2;
            __builtin_amdgcn_global_load_lds(
                (const __attribute__((address_space(1))) void*)s2,
                (__attribute__((address_space(3))) void*)(slot + i2 * 4), 16, 0, 0);
        }
    };

    issue(0);
    issue(1);

    for (int r = 0; r < 18; ++r) {
        // wait own loads of row r (row r+1 stays in flight); waves 0,1 issued
        // 2 instrs/row, waves 2,3 issued 1 (wave-uniform branch).
        if (r < 16) {
            if (wv < 2) asm volatile("s_waitcnt vmcnt(2)" ::: "memory");
            else        asm volatile("s_waitcnt vmcnt(1)" ::: "memory");
        } else {
            asm volatile("s_waitcnt vmcnt(0)" ::: "memory");
        }
        __builtin_amdgcn_s_barrier();
        __builtin_amdgcn_sched_barrier(0);

        const bool rv = (unsigned)(h0 - 1 + r) < 256u;
        const float* rf = raw + ((r & 1) ? 1536 : 0);

        // transpose: 288 tasks (18 px x 8 granules x 2 halves)
        auto xpose = [&](int t0) {
            const int px = t0 >> 4, sub = t0 & 15;
            const int g = sub >> 1, h2 = sub & 1;
            const int w = w0 - 1 + px;
            const bool ok = rv && ((unsigned)w < 256u);
            const int base = 96 * ((g << 1) + h2) + px + 3;  // c0=8g+4h2; c0*24+col
            float f0 = ok ? rf[base]      : 0.f;
            float f1 = ok ? rf[base + 24] : 0.f;
            float f2 = ok ? rf[base + 48] : 0.f;
            float f3 = ok ? rf[base + 72] : 0.f;
            union { v2h h; u32 u; } pA, pB;
            pA.h[0] = (_Float16)f0; pA.h[1] = (_Float16)f1;
            pB.h[0] = (_Float16)f2; pB.h[1] = (_Float16)f3;
            const int pixg = r * 18 + px;
            u32* dst = reinterpret_cast<u32*>(
                reinterpret_cast<char*>(lt) + pixg * 128
                + ((g ^ (pixg & 7)) << 4) + (h2 << 3));
            dst[0] = pA.u; dst[1] = pB.u;
        };
        xpose(tid);
        if (tid < 32) xpose(256 + tid);

        asm volatile("s_waitcnt lgkmcnt(0)" ::: "memory");
        __builtin_amdgcn_s_barrier();
        if (r + 2 < 18) issue(r + 2);
    }
    __builtin_amdgcn_sched_barrier(0);

    // ---- compute phase (round-2 verified structure, 16x16 tile)
    const int n = lane & 15, lg = lane >> 4;
    const _Float16* wab = wA + (size_t)b * 36864;

    v4f acc[4][4];
    #pragma unroll
    for (int ot = 0; ot < 4; ++ot)
        #pragma unroll
        for (int rq = 0; rq < 4; ++rq)
            acc[ot][rq] = (v4f)0.f;

    #pragma unroll
    for (int t = 0; t < 9; ++t) {
        const int dh = t / 3, dw = t - dh * 3;
        v8h a[4][2];
        #pragma unroll
        for (int ot = 0; ot < 4; ++ot)
            #pragma unroll
            for (int ks = 0; ks < 2; ++ks)
                a[ot][ks] = *reinterpret_cast<const v8h*>(
                    wab + ((size_t)((t * 8 + ks * 4 + ot) * 64 + lane)) * 8);
        #pragma unroll
        for (int rq = 0; rq < 4; ++rq) {
            const int row = (wv << 2) + rq;
            const int pix = (row + dh) * 18 + n + dw;
            const char* pb = reinterpret_cast<const char*>(lt) + pix * 128;
            const int px7 = pix & 7;
            #pragma unroll
            for (int ks = 0; ks < 2; ++ks) {
                v8h bf = *reinterpret_cast<const v8h*>(
                    pb + ((((ks << 2) + lg) ^ px7) << 4));
                #pragma unroll
                for (int ot = 0; ot < 4; ++ot)
                    acc[ot][rq] = __builtin_amdgcn_mfma_f32_16x16x32_f16(
                        a[ot][ks], bf, acc[ot][rq], 0, 0, 0);
            }
        }
    }

    // ---- epilogue: D row=(l>>4)*4+reg (o), col=l&15 (w)
    #pragma unroll
    for (int ot = 0; ot < 4; ++ot) {
        #pragma unroll
        for (int rq = 0; rq < 4; ++rq) {
            const int h = h0 + (wv << 2) + rq;
            #pragma unroll
            for (int reg = 0; reg < 4; ++reg) {
                const int o = (ot << 4) + (lg << 2) + reg;
                out[((size_t)(b * 64 + o) << 16) + (h << 8) + w0 + n] = acc[ot][rq][reg];
            }
        }
    }
}

extern "C" void kernel_launch(void* const* d_in, const int* in_sizes, int n_in,
                              void* d_out, int out_size, void* d_ws, size_t ws_size,
                              hipStream_t stream) {
    const float* x      = (const float*)d_in[0];
    const float* style  = (const float*)d_in[1];
    const float* mw     = (const float*)d_in[2];
    const float* mb     = (const float*)d_in[3];
    const float* weight = (const float*)d_in[4];
    float* out = (float*)d_out;

    float*    s_ws = (float*)d_ws;                       // 1 KB used
    _Float16* wA   = (_Float16*)((char*)d_ws + 4096);    // 1.18 MB

    style_kernel<<<16, 256, 0, stream>>>(style, mw, mb, s_ws);
    wprep_kernel<<<1024, 64, 0, stream>>>(weight, s_ws, wA);
    conv_fused<<<dim3(16, 16, 16), 256, 0, stream>>>(x, wA, out);
}

// Round 13
// 253.863 us; speedup vs baseline: 1.2653x; 1.2653x over previous
//
#include <hip/hip_runtime.h>

typedef _Float16 v8h __attribute__((ext_vector_type(8)));
typedef _Float16 v2h __attribute__((ext_vector_type(2)));
typedef float    v4f __attribute__((ext_vector_type(4)));
typedef unsigned int u32;

// ---------------- Kernel 1: style modulation s[b][c] = style[b]·mod_weight[c] + bias[c]
__global__ void style_kernel(const float* __restrict__ style,
                             const float* __restrict__ mw,
                             const float* __restrict__ mb,
                             float* __restrict__ s_out) {
    const int b = blockIdx.x;          // 16 blocks
    const int t = threadIdx.x;         // 256 threads
    const int c = t >> 2, q = t & 3;   // 4 threads per channel, 128 elems each
    const float* st = style + b * 512 + q * 128;
    const float* w  = mw + c * 512 + q * 128;
    float acc = 0.f;
    #pragma unroll 8
    for (int i = 0; i < 128; ++i) acc += st[i] * w[i];
    acc += __shfl_xor(acc, 1);
    acc += __shfl_xor(acc, 2);
    if (q == 0) s_out[b * 64 + c] = acc + mb[c];
}

// ---------------- Kernel 2: modulate + demodulate + repack weights into A-fragment layout
// wA layout: [b][tap][ks*4+ot][lane][j] (f16): lane l holds o = ot*16 + (l&15),
// k(channel) = ks*32 + (l>>4)*8 + j  -> mfma_f32_16x16x32 A-operand layout.
__global__ void wprep_kernel(const float* __restrict__ weight,
                             const float* __restrict__ s,
                             _Float16* __restrict__ wA) {
    const int blk = blockIdx.x;            // 1024 = B*O
    const int b = blk >> 6, o = blk & 63;
    const int lane = threadIdx.x;          // 64
    const float* wo = weight + o * 576;    // weight[0][o][c][kh][kw]
    const float* sb = s + b * 64;
    float vals[9];
    float sum = 0.f;
    #pragma unroll
    for (int k = 0; k < 9; ++k) {
        int e = lane + k * 64;             // 0..575
        int c = e / 9;
        float v = wo[e] * sb[c];
        vals[k] = v;
        sum += v * v;
    }
    #pragma unroll
    for (int off = 32; off; off >>= 1) sum += __shfl_xor(sum, off);
    const float demod = 1.f / sqrtf(sum + 1e-8f);
    #pragma unroll
    for (int k = 0; k < 9; ++k) {
        int e = lane + k * 64;
        int c = e / 9, tap = e - c * 9;
        int ks = c >> 5, lg = (c >> 3) & 3, j = c & 7;
        int dst = (((b * 9 + tap) * 8 + ks * 4 + (o >> 4)) * 64 + lg * 16 + (o & 15)) * 8 + j;
        wA[dst] = (_Float16)(vals[k] * demod);
    }
}

// ---------------- Kernel 2b: interior transpose x NCHW f32 -> padded NHWC f16.
// 4 rows per block: each block reads 4KB CONTIGUOUS per channel plane (DRAM page
// locality) via v4f loads (16B/lane, 1KB/wave-instr). LDS transpose per row;
// stores are 1KB-contiguous per wave-instr (full 128B lines, no RMW).
__global__ __launch_bounds__(256)
void xprep_kernel(const float* __restrict__ x, _Float16* __restrict__ xh) {
    __shared__ u32 lt[32 * 257];   // [cpair][w + pad] : 32896 B
    const int tid = threadIdx.x;
    const int wq = tid & 63;       // w base = 4*wq
    const int cg = tid >> 6;       // channel group: c = 16*cg + j
    const int h0 = blockIdx.x << 2;
    const int b  = blockIdx.y;
    const float* xb = x + ((size_t)b << 22);

    for (int sub = 0; sub < 4; ++sub) {
        const int h = h0 + sub;
        v4f f[16];
        #pragma unroll
        for (int j = 0; j < 16; ++j) {
            const int c = (cg << 4) + j;
            f[j] = *reinterpret_cast<const v4f*>(xb + ((size_t)c << 16) + (h << 8) + (wq << 2));
        }
        if (sub) __syncthreads();   // prior phase-2 readers done before overwrite
        #pragma unroll
        for (int jp = 0; jp < 8; ++jp) {
            const int cp = (cg << 3) + jp;
            #pragma unroll
            for (int k = 0; k < 4; ++k) {
                union { v2h h2; u32 u; } pk;
                pk.h2[0] = (_Float16)f[2 * jp][k];
                pk.h2[1] = (_Float16)f[2 * jp + 1][k];
                lt[cp * 257 + (wq << 2) + k] = pk.u;
            }
        }
        __syncthreads();
        _Float16* rowb = xh + ((size_t)(b * 258 + h + 1) * 258 + 1) * 64;
        #pragma unroll
        for (int k = 0; k < 8; ++k) {
            const int G = (k << 8) + tid;     // granule id: pix*8 + g
            const int pix = G >> 3, g = G & 7;
            union { u32 u[4]; v8h h8; } as_;
            #pragma unroll
            for (int jj = 0; jj < 4; ++jj)
                as_.u[jj] = lt[(4 * g + jj) * 257 + pix];
            *reinterpret_cast<v8h*>(rowb + (size_t)G * 8) = as_.h8;
        }
    }
}

// ---------------- Kernel 2c: zero the padded border of xh
__global__ __launch_bounds__(256)
void xborder_kernel(_Float16* __restrict__ xh) {
    const int b = blockIdx.x;
    const int tid = threadIdx.x;
    _Float16* xb = xh + (size_t)b * (258 * 258 * 64);
    for (int it = 0; it < 5; ++it) {
        int idx = it * 256 + tid;
        if (idx >= 1028) break;
        int row, col;
        if (idx < 258)        { row = 0;            col = idx; }
        else if (idx < 516)   { row = 257;          col = idx - 258; }
        else if (idx < 772)   { row = idx - 516 + 1; col = 0; }
        else                  { row = idx - 772 + 1; col = 257; }
        v8h z = {};
        _Float16* p = xb + (size_t)(row * 258 + col) * 64;
        #pragma unroll
        for (int g = 0; g < 8; ++g)
            *reinterpret_cast<v8h*>(p + g * 8) = z;
    }
}

// ---------------- Kernel 3: implicit-GEMM conv, 32x16 tile, 2-chunk pipelined staging
// (byte-identical to round 5/6/9 — measured ~115 µs)
__global__ __launch_bounds__(256, 2)
void conv_kernel(const _Float16* __restrict__ xh,
                 const _Float16* __restrict__ wA,
                 float* __restrict__ out) {
    __shared__ __align__(16) _Float16 lds[612 * 64];   // 78336 B

    const int tid = threadIdx.x;
    const int fid = blockIdx.x + (blockIdx.y << 3) + (blockIdx.z << 7);
    const int vid = ((fid & 7) << 8) + (fid >> 3);
    const int tx = vid & 7;          // w-tile (32 wide)
    const int ty = (vid >> 3) & 15;  // h-tile (16 high)
    const int b  = vid >> 7;

    const int h0 = ty << 4;
    const int w0 = tx << 5;

    const int lane = tid & 63, wv = tid >> 6;
    const _Float16* xhb = xh + (size_t)b * (258 * 258 * 64);

    #pragma unroll
    for (int i = 0; i < 11; ++i) {
        const int k = wv + (i << 2);
        const int g0 = (k < 43) ? ((k << 6) < 2656 ? (k << 6) : 2656) : 0;
        const int A = g0 + lane;
        const int pix = A >> 3, g = A & 7;
        const int ph = pix / 34, pw = pix - ph * 34;
        const _Float16* src = xhb + (size_t)((h0 + ph) * 258 + (w0 + pw)) * 64
                                  + ((g ^ (pix & 7)) << 3);
        __builtin_amdgcn_global_load_lds(
            (const __attribute__((address_space(1))) void*)src,
            (__attribute__((address_space(3))) void*)(lds + (size_t)A * 8),
            16, 0, 0);
    }
    #pragma unroll
    for (int i = 0; i < 9; ++i) {
        const int k = wv + (i << 2);
        const int g0 = 2720 + ((k < 34) ? (k << 6) : 0);
        const int A = g0 + lane;
        const int pix = A >> 3, g = A & 7;
        const int ph = pix / 34, pw = pix - ph * 34;
        const _Float16* src = xhb + (size_t)((h0 + ph) * 258 + (w0 + pw)) * 64
                                  + ((g ^ (pix & 7)) << 3);
        __builtin_amdgcn_global_load_lds(
            (const __attribute__((address_space(1))) void*)src,
            (__attribute__((address_space(3))) void*)(lds + (size_t)A * 8),
            16, 0, 0);
    }

    const int n = lane & 15, lg = lane >> 4;
    const _Float16* wab = wA + (size_t)b * (9 * 8 * 64 * 8);

    v4f acc[4][2][2];   // [ot][hf][rq]

    asm volatile("s_waitcnt vmcnt(9)" ::: "memory");
    __builtin_amdgcn_s_barrier();
    __builtin_amdgcn_sched_barrier(0);

    // ---- pair 0: out rows wv, wv+4 (halo rows <= 9)
    #pragma unroll
    for (int ot = 0; ot < 4; ++ot)
        #pragma unroll
        for (int hf = 0; hf < 2; ++hf)
            #pragma unroll
            for (int rq = 0; rq < 2; ++rq)
                acc[ot][hf][rq] = (v4f)0.f;

    #pragma unroll
    for (int t = 0; t < 9; ++t) {
        const int dh = t / 3, dw = t - dh * 3;
        v8h a[4][2];
        #pragma unroll
        for (int ot = 0; ot < 4; ++ot)
            #pragma unroll
            for (int ks = 0; ks < 2; ++ks)
                a[ot][ks] = *reinterpret_cast<const v8h*>(
                    wab + ((size_t)((t * 8 + ks * 4 + ot) * 64 + lane)) * 8);
        #pragma unroll
        for (int rq = 0; rq < 2; ++rq) {
            const int R = wv + (rq << 2);
            #pragma unroll
            for (int hf = 0; hf < 2; ++hf) {
                const int pix = (R + dh) * 34 + n + (hf << 4) + dw;
                const char* pb = reinterpret_cast<const char*>(lds) + pix * 128;
                const int px7 = pix & 7;
                #pragma unroll
                for (int ks = 0; ks < 2; ++ks) {
                    v8h bf = *reinterpret_cast<const v8h*>(
                        pb + ((((ks << 2) + lg) ^ px7) << 4));
                    #pragma unroll
                    for (int ot = 0; ot < 4; ++ot)
                        acc[ot][hf][rq] = __builtin_amdgcn_mfma_f32_16x16x32_f16(
                            a[ot][ks], bf, acc[ot][hf][rq], 0, 0, 0);
                }
            }
        }
    }

    asm volatile("s_waitcnt vmcnt(0)" ::: "memory");
    __builtin_amdgcn_s_barrier();
    __builtin_amdgcn_sched_barrier(0);

    #pragma unroll
    for (int ot = 0; ot < 4; ++ot) {
        #pragma unroll
        for (int rq = 0; rq < 2; ++rq) {
            const int h = h0 + wv + (rq << 2);
            #pragma unroll
            for (int reg = 0; reg < 4; ++reg) {
                const int o = (ot << 4) + (lg << 2) + reg;
                float* op = out + (((size_t)(b * 64 + o)) << 16) + (h << 8) + w0 + n;
                op[0]  = acc[ot][0][rq][reg];
                op[16] = acc[ot][1][rq][reg];
            }
        }
    }

    // ---- pair 1: out rows wv+8, wv+12 (halo rows 8..17)
    #pragma unroll
    for (int ot = 0; ot < 4; ++ot)
        #pragma unroll
        for (int hf = 0; hf < 2; ++hf)
            #pragma unroll
            for (int rq = 0; rq < 2; ++rq)
                acc[ot][hf][rq] = (v4f)0.f;

    #pragma unroll
    for (int t = 0; t < 9; ++t) {
        const int dh = t / 3, dw = t - dh * 3;
        v8h a[4][2];
        #pragma unroll
        for (int ot = 0; ot < 4; ++ot)
            #pragma unroll
            for (int ks = 0; ks < 2; ++ks)
                a[ot][ks] = *reinterpret_cast<const v8h*>(
                    wab + ((size_t)((t * 8 + ks * 4 + ot) * 64 + lane)) * 8);
        #pragma unroll
        for (int rq = 0; rq < 2; ++rq) {
            const int R = wv + 8 + (rq << 2);
            #pragma unroll
            for (int hf = 0; hf < 2; ++hf) {
                const int pix = (R + dh) * 34 + n + (hf << 4) + dw;
                const char* pb = reinterpret_cast<const char*>(lds) + pix * 128;
                const int px7 = pix & 7;
                #pragma unroll
                for (int ks = 0; ks < 2; ++ks) {
                    v8h bf = *reinterpret_cast<const v8h*>(
                        pb + ((((ks << 2) + lg) ^ px7) << 4));
                    #pragma unroll
                    for (int ot = 0; ot < 4; ++ot)
                        acc[ot][hf][rq] = __builtin_amdgcn_mfma_f32_16x16x32_f16(
                            a[ot][ks], bf, acc[ot][hf][rq], 0, 0, 0);
                }
            }
        }
    }

    #pragma unroll
    for (int ot = 0; ot < 4; ++ot) {
        #pragma unroll
        for (int rq = 0; rq < 2; ++rq) {
            const int h = h0 + wv + 8 + (rq << 2);
            #pragma unroll
            for (int reg = 0; reg < 4; ++reg) {
                const int o = (ot << 4) + (lg << 2) + reg;
                float* op = out + (((size_t)(b * 64 + o)) << 16) + (h << 8) + w0 + n;
                op[0]  = acc[ot][0][rq][reg];
                op[16] = acc[ot][1][rq][reg];
            }
        }
    }
}

extern "C" void kernel_launch(void* const* d_in, const int* in_sizes, int n_in,
                              void* d_out, int out_size, void* d_ws, size_t ws_size,
                              hipStream_t stream) {
    const float* x      = (const float*)d_in[0];
    const float* style  = (const float*)d_in[1];
    const float* mw     = (const float*)d_in[2];
    const float* mb     = (const float*)d_in[3];
    const float* weight = (const float*)d_in[4];
    float* out = (float*)d_out;

    float*    s_ws = (float*)d_ws;                       // 1 KB used
    _Float16* wA   = (_Float16*)((char*)d_ws + 4096);    // 1.18 MB
    _Float16* xh   = (_Float16*)((char*)d_ws + 2u * 1024u * 1024u);  // 136.3 MB

    style_kernel<<<16, 256, 0, stream>>>(style, mw, mb, s_ws);
    wprep_kernel<<<1024, 64, 0, stream>>>(weight, s_ws, wA);
    xborder_kernel<<<16, 256, 0, stream>>>(xh);
    xprep_kernel<<<dim3(64, 16), 256, 0, stream>>>(x, xh);
    conv_kernel<<<dim3(8, 16, 16), 256, 0, stream>>>(xh, wA, out);
}

// Round 14
// 188.603 us; speedup vs baseline: 1.7031x; 1.3460x over previous
//
#include <hip/hip_runtime.h>

typedef _Float16 v8h __attribute__((ext_vector_type(8)));
typedef _Float16 v2h __attribute__((ext_vector_type(2)));
typedef float    v4f __attribute__((ext_vector_type(4)));
typedef unsigned int u32;

// ---------------- Kernel 1: style modulation s[b][c] = style[b]·mod_weight[c] + bias[c]
__global__ void style_kernel(const float* __restrict__ style,
                             const float* __restrict__ mw,
                             const float* __restrict__ mb,
                             float* __restrict__ s_out) {
    const int b = blockIdx.x;          // 16 blocks
    const int t = threadIdx.x;         // 256 threads
    const int c = t >> 2, q = t & 3;   // 4 threads per channel, 128 elems each
    const float* st = style + b * 512 + q * 128;
    const float* w  = mw + c * 512 + q * 128;
    float acc = 0.f;
    #pragma unroll 8
    for (int i = 0; i < 128; ++i) acc += st[i] * w[i];
    acc += __shfl_xor(acc, 1);
    acc += __shfl_xor(acc, 2);
    if (q == 0) s_out[b * 64 + c] = acc + mb[c];
}

// ---------------- Kernel 2: modulate + demodulate + repack weights into A-fragment layout
// wA layout: [b][tap][ks*4+ot][lane][j] (f16): lane l holds o = ot*16 + (l&15),
// k(channel) = ks*32 + (l>>4)*8 + j  -> mfma_f32_16x16x32 A-operand layout.
__global__ void wprep_kernel(const float* __restrict__ weight,
                             const float* __restrict__ s,
                             _Float16* __restrict__ wA) {
    const int blk = blockIdx.x;            // 1024 = B*O
    const int b = blk >> 6, o = blk & 63;
    const int lane = threadIdx.x;          // 64
    const float* wo = weight + o * 576;    // weight[0][o][c][kh][kw]
    const float* sb = s + b * 64;
    float vals[9];
    float sum = 0.f;
    #pragma unroll
    for (int k = 0; k < 9; ++k) {
        int e = lane + k * 64;             // 0..575
        int c = e / 9;
        float v = wo[e] * sb[c];
        vals[k] = v;
        sum += v * v;
    }
    #pragma unroll
    for (int off = 32; off; off >>= 1) sum += __shfl_xor(sum, off);
    const float demod = 1.f / sqrtf(sum + 1e-8f);
    #pragma unroll
    for (int k = 0; k < 9; ++k) {
        int e = lane + k * 64;
        int c = e / 9, tap = e - c * 9;
        int ks = c >> 5, lg = (c >> 3) & 3, j = c & 7;
        int dst = (((b * 9 + tap) * 8 + ks * 4 + (o >> 4)) * 64 + lg * 16 + (o & 15)) * 8 + j;
        wA[dst] = (_Float16)(vals[k] * demod);
    }
}

// ---------------- Kernel 2b: interior transpose x NCHW f32 -> padded NHWC f16.
// (r9 structure, best measured.) x reads NON-TEMPORAL (read-once stream; keep
// L3 for xh). Border zeroing folded in (tid<5 path). Phase 2 stores 1KB
// contiguous per wave-instr (full 128B lines, no RMW).
__global__ __launch_bounds__(256)
void xprep_kernel(const float* __restrict__ x, _Float16* __restrict__ xh) {
    __shared__ u32 lt[32 * 257];   // [cpair][w + pad] : 32896 B
    const int tid = threadIdx.x;
    const int h = blockIdx.x;    // 0..255
    const int b = blockIdx.y;

    const float* xr = x + ((size_t)b << 22) + (h << 8) + tid;   // w = tid
    float va[64];
    #pragma unroll
    for (int c = 0; c < 64; ++c)
        va[c] = __builtin_nontemporal_load(&xr[(size_t)c << 16]);
    #pragma unroll
    for (int cp = 0; cp < 32; ++cp) {
        union { v2h h2; u32 u; } pk;
        pk.h2[0] = (_Float16)va[2 * cp];
        pk.h2[1] = (_Float16)va[2 * cp + 1];
        lt[cp * 257 + tid] = pk.u;
    }

    // folded border zeroing: 1028 border pixel-lines per batch over 256 blocks
    if (tid < 5) {
        const int idx = blockIdx.x * 5 + tid;
        if (idx < 1028) {
            int row, col;
            if (idx < 258)        { row = 0;             col = idx; }
            else if (idx < 516)   { row = 257;           col = idx - 258; }
            else if (idx < 772)   { row = idx - 516 + 1; col = 0; }
            else                  { row = idx - 772 + 1; col = 257; }
            v8h z = {};
            _Float16* p = xh + (size_t)b * (258 * 258 * 64)
                             + (size_t)(row * 258 + col) * 64;
            #pragma unroll
            for (int g = 0; g < 8; ++g)
                *reinterpret_cast<v8h*>(p + g * 8) = z;
        }
    }
    __syncthreads();

    // pixel row base in xh (f16 units): interior pixel (h+1, w=1..256)
    _Float16* rowb = xh + ((size_t)(b * 258 + h + 1) * 258 + 1) * 64;
    #pragma unroll
    for (int k = 0; k < 8; ++k) {
        const int G = (k << 8) + tid;     // granule id: pix*8 + g
        const int pix = G >> 3, g = G & 7;
        union { u32 u[4]; v8h h8; } as_;
        #pragma unroll
        for (int jj = 0; jj < 4; ++jj)
            as_.u[jj] = lt[(4 * g + jj) * 257 + pix];
        *reinterpret_cast<v8h*>(rowb + (size_t)G * 8) = as_.h8;
    }
}

// ---------------- Kernel 3: implicit-GEMM conv, 32x16 tile, 2-chunk pipelined staging
// (r9 structure, measured ~115 µs) + NON-TEMPORAL out stores (write-once stream;
// keep L2/L3 for xh reads).
__global__ __launch_bounds__(256, 2)
void conv_kernel(const _Float16* __restrict__ xh,
                 const _Float16* __restrict__ wA,
                 float* __restrict__ out) {
    __shared__ __align__(16) _Float16 lds[612 * 64];   // 78336 B

    const int tid = threadIdx.x;
    const int fid = blockIdx.x + (blockIdx.y << 3) + (blockIdx.z << 7);
    const int vid = ((fid & 7) << 8) + (fid >> 3);
    const int tx = vid & 7;          // w-tile (32 wide)
    const int ty = (vid >> 3) & 15;  // h-tile (16 high)
    const int b  = vid >> 7;

    const int h0 = ty << 4;
    const int w0 = tx << 5;

    const int lane = tid & 63, wv = tid >> 6;
    const _Float16* xhb = xh + (size_t)b * (258 * 258 * 64);

    #pragma unroll
    for (int i = 0; i < 11; ++i) {
        const int k = wv + (i << 2);
        const int g0 = (k < 43) ? ((k << 6) < 2656 ? (k << 6) : 2656) : 0;
        const int A = g0 + lane;
        const int pix = A >> 3, g = A & 7;
        const int ph = pix / 34, pw = pix - ph * 34;
        const _Float16* src = xhb + (size_t)((h0 + ph) * 258 + (w0 + pw)) * 64
                                  + ((g ^ (pix & 7)) << 3);
        __builtin_amdgcn_global_load_lds(
            (const __attribute__((address_space(1))) void*)src,
            (__attribute__((address_space(3))) void*)(lds + (size_t)A * 8),
            16, 0, 0);
    }
    #pragma unroll
    for (int i = 0; i < 9; ++i) {
        const int k = wv + (i << 2);
        const int g0 = 2720 + ((k < 34) ? (k << 6) : 0);
        const int A = g0 + lane;
        const int pix = A >> 3, g = A & 7;
        const int ph = pix / 34, pw = pix - ph * 34;
        const _Float16* src = xhb + (size_t)((h0 + ph) * 258 + (w0 + pw)) * 64
                                  + ((g ^ (pix & 7)) << 3);
        __builtin_amdgcn_global_load_lds(
            (const __attribute__((address_space(1))) void*)src,
            (__attribute__((address_space(3))) void*)(lds + (size_t)A * 8),
            16, 0, 0);
    }

    const int n = lane & 15, lg = lane >> 4;
    const _Float16* wab = wA + (size_t)b * (9 * 8 * 64 * 8);

    v4f acc[4][2][2];   // [ot][hf][rq]

    asm volatile("s_waitcnt vmcnt(9)" ::: "memory");
    __builtin_amdgcn_s_barrier();
    __builtin_amdgcn_sched_barrier(0);

    // ---- pair 0: out rows wv, wv+4 (halo rows <= 9)
    #pragma unroll
    for (int ot = 0; ot < 4; ++ot)
        #pragma unroll
        for (int hf = 0; hf < 2; ++hf)
            #pragma unroll
            for (int rq = 0; rq < 2; ++rq)
                acc[ot][hf][rq] = (v4f)0.f;

    #pragma unroll
    for (int t = 0; t < 9; ++t) {
        const int dh = t / 3, dw = t - dh * 3;
        v8h a[4][2];
        #pragma unroll
        for (int ot = 0; ot < 4; ++ot)
            #pragma unroll
            for (int ks = 0; ks < 2; ++ks)
                a[ot][ks] = *reinterpret_cast<const v8h*>(
                    wab + ((size_t)((t * 8 + ks * 4 + ot) * 64 + lane)) * 8);
        #pragma unroll
        for (int rq = 0; rq < 2; ++rq) {
            const int R = wv + (rq << 2);
            #pragma unroll
            for (int hf = 0; hf < 2; ++hf) {
                const int pix = (R + dh) * 34 + n + (hf << 4) + dw;
                const char* pb = reinterpret_cast<const char*>(lds) + pix * 128;
                const int px7 = pix & 7;
                #pragma unroll
                for (int ks = 0; ks < 2; ++ks) {
                    v8h bf = *reinterpret_cast<const v8h*>(
                        pb + ((((ks << 2) + lg) ^ px7) << 4));
                    #pragma unroll
                    for (int ot = 0; ot < 4; ++ot)
                        acc[ot][hf][rq] = __builtin_amdgcn_mfma_f32_16x16x32_f16(
                            a[ot][ks], bf, acc[ot][hf][rq], 0, 0, 0);
                }
            }
        }
    }

    asm volatile("s_waitcnt vmcnt(0)" ::: "memory");
    __builtin_amdgcn_s_barrier();
    __builtin_amdgcn_sched_barrier(0);

    #pragma unroll
    for (int ot = 0; ot < 4; ++ot) {
        #pragma unroll
        for (int rq = 0; rq < 2; ++rq) {
            const int h = h0 + wv + (rq << 2);
            #pragma unroll
            for (int reg = 0; reg < 4; ++reg) {
                const int o = (ot << 4) + (lg << 2) + reg;
                float* op = out + (((size_t)(b * 64 + o)) << 16) + (h << 8) + w0 + n;
                __builtin_nontemporal_store(acc[ot][0][rq][reg], op);
                __builtin_nontemporal_store(acc[ot][1][rq][reg], op + 16);
            }
        }
    }

    // ---- pair 1: out rows wv+8, wv+12 (halo rows 8..17)
    #pragma unroll
    for (int ot = 0; ot < 4; ++ot)
        #pragma unroll
        for (int hf = 0; hf < 2; ++hf)
            #pragma unroll
            for (int rq = 0; rq < 2; ++rq)
                acc[ot][hf][rq] = (v4f)0.f;

    #pragma unroll
    for (int t = 0; t < 9; ++t) {
        const int dh = t / 3, dw = t - dh * 3;
        v8h a[4][2];
        #pragma unroll
        for (int ot = 0; ot < 4; ++ot)
            #pragma unroll
            for (int ks = 0; ks < 2; ++ks)
                a[ot][ks] = *reinterpret_cast<const v8h*>(
                    wab + ((size_t)((t * 8 + ks * 4 + ot) * 64 + lane)) * 8);
        #pragma unroll
        for (int rq = 0; rq < 2; ++rq) {
            const int R = wv + 8 + (rq << 2);
            #pragma unroll
            for (int hf = 0; hf < 2; ++hf) {
                const int pix = (R + dh) * 34 + n + (hf << 4) + dw;
                const char* pb = reinterpret_cast<const char*>(lds) + pix * 128;
                const int px7 = pix & 7;
                #pragma unroll
                for (int ks = 0; ks < 2; ++ks) {
                    v8h bf = *reinterpret_cast<const v8h*>(
                        pb + ((((ks << 2) + lg) ^ px7) << 4));
                    #pragma unroll
                    for (int ot = 0; ot < 4; ++ot)
                        acc[ot][hf][rq] = __builtin_amdgcn_mfma_f32_16x16x32_f16(
                            a[ot][ks], bf, acc[ot][hf][rq], 0, 0, 0);
                }
            }
        }
    }

    #pragma unroll
    for (int ot = 0; ot < 4; ++ot) {
        #pragma unroll
        for (int rq = 0; rq < 2; ++rq) {
            const int h = h0 + wv + 8 + (rq << 2);
            #pragma unroll
            for (int reg = 0; reg < 4; ++reg) {
                const int o = (ot << 4) + (lg << 2) + reg;
                float* op = out + (((size_t)(b * 64 + o)) << 16) + (h << 8) + w0 + n;
                __builtin_nontemporal_store(acc[ot][0][rq][reg], op);
                __builtin_nontemporal_store(acc[ot][1][rq][reg], op + 16);
            }
        }
    }
}

extern "C" void kernel_launch(void* const* d_in, const int* in_sizes, int n_in,
                              void* d_out, int out_size, void* d_ws, size_t ws_size,
                              hipStream_t stream) {
    const float* x      = (const float*)d_in[0];
    const float* style  = (const float*)d_in[1];
    const float* mw     = (const float*)d_in[2];
    const float* mb     = (const float*)d_in[3];
    const float* weight = (const float*)d_in[4];
    float* out = (float*)d_out;

    float*    s_ws = (float*)d_ws;                       // 1 KB used
    _Float16* wA   = (_Float16*)((char*)d_ws + 4096);    // 1.18 MB
    _Float16* xh   = (_Float16*)((char*)d_ws + 2u * 1024u * 1024u);  // 136.3 MB

    style_kernel<<<16, 256, 0, stream>>>(style, mw, mb, s_ws);
    wprep_kernel<<<1024, 64, 0, stream>>>(weight, s_ws, wA);
    xprep_kernel<<<dim3(256, 16), 256, 0, stream>>>(x, xh);
    conv_kernel<<<dim3(8, 16, 16), 256, 0, stream>>>(xh, wA, out);
}